// Round 12
// baseline (321.286 us; speedup 1.0000x reference)
//
#include <hip/hip_runtime.h>
#include <math.h>

#define F 128
#define THREEF 384
#define N_RBF 20
#define CUTOFF 5.0f
#define CAP 64
#define TLDS_STRIDE 136   // shorts; 272 B row: 16B-aligned, ~2-way banks (free)
#define ASTRIDE 392       // A_lds row stride (fp16): 784 B -> 2-way write banks

typedef __bf16 bf16x8 __attribute__((ext_vector_type(8)));
typedef float  f32x4  __attribute__((ext_vector_type(4)));
typedef _Float16 f16x2 __attribute__((ext_vector_type(2)));

static __device__ __forceinline__ float loh(unsigned int u) {
    const f16x2 h = __builtin_bit_cast(f16x2, u);
    return (float)h[0];
}
static __device__ __forceinline__ float hih(unsigned int u) {
    const f16x2 h = __builtin_bit_cast(f16x2, u);
    return (float)h[1];
}

// ---------------------------------------------------------------------------
// Init:
//   blocks [0,256)      : wcast — W1,W2 -> bf16 k-major
//   blocks [256,304)    : w2c — W2C[col][k] = Wr[k][col] (k<20), 0 pad (384x32)
//   blocks [304,304+ZB) : zero cnt
// ---------------------------------------------------------------------------
__global__ __launch_bounds__(256) void init_kernel(
    const float* __restrict__ W1, const float* __restrict__ W2,
    const float* __restrict__ Wr,
    __bf16* __restrict__ W1T, __bf16* __restrict__ W2T,
    __bf16* __restrict__ W2C, int* __restrict__ cnt, int N)
{
    const int tid = threadIdx.x;
    const int b   = blockIdx.x;

    if (b < 256) {                      // ---- wcast
        const int idx = b * 256 + tid;
        if (idx < 128 * 128) {
            const int n = idx >> 7, k = idx & 127;
            W1T[idx] = (__bf16)W1[k * F + n];
        }
        if (idx < 384 * 128) {
            const int n = idx >> 7, k = idx & 127;
            W2T[idx] = (__bf16)W2[k * THREEF + n];
        }
    } else if (b < 304) {               // ---- w2c: (384 cols x 32 k) bf16
        const int idx = (b - 256) * 256 + tid;   // 0..12287
        const int col = idx >> 5, k = idx & 31;
        W2C[idx] = (k < N_RBF) ? (__bf16)Wr[k * THREEF + col] : (__bf16)0.0f;
    } else {                            // ---- zero cnt
        const int i = (b - 304) * 256 + tid;
        if (i < (N + 3) / 4) {
            int4 z; z.x = 0; z.y = 0; z.z = 0; z.w = 0;
            ((int4*)cnt)[i] = z;
        }
    }
}

// ---------------------------------------------------------------------------
// Work (build ∥ mlp ∥ vcast as CONCURRENT block ranges):
//   blocks [0, EB)           : build — pack row at (dst,slot):
//                              {sin(x), 2cos(x), fcut, ux, uy, uz, src, fcut/d}
//                              (R12: sine UNSCALED for bf16 MFMA; scale fp32)
//   blocks [EB, EB+MB)       : mlp — phi via bf16 MFMA, fp16 into gh record
//   blocks [EB+MB, EB+MB+VB) : vcast — v_i fp32 -> fp16 into gh record
// gh = (N,128,6) fp16 {phi0,phi1,phi2,vx,vy,vz}  (R10, verified: FETCH /2)
// ---------------------------------------------------------------------------
__global__ __launch_bounds__(256) void work_kernel(
    const float* __restrict__ d_ij, const float* __restrict__ unit_r,
    const int* __restrict__ nbrs, const float* __restrict__ v_i,
    int* __restrict__ cnt, float* __restrict__ pack,
    const float* __restrict__ h,
    const __bf16* __restrict__ W1T, const float* __restrict__ b1,
    const __bf16* __restrict__ W2T, const float* __restrict__ b2,
    _Float16* __restrict__ gh, int E, int EB, int MB, int N)
{
    __shared__ __bf16 t_lds[16 * TLDS_STRIDE];   // mlp only; 4.3 KB

    const int tid = threadIdx.x;
    const int b   = blockIdx.x;

    if (b < EB) {                       // ---- build
        const int e = b * 256 + tid;
        if (e >= E) return;
        const int2 nb = ((const int2*)nbrs)[e];
        const int dst = nb.x;
        const int src = nb.y;
        const int slot = atomicAdd(&cnt[dst], 1);
        if (slot >= CAP) return;

        const float d = d_ij[e];
        const float x = (float)M_PI * d * (1.0f / CUTOFF);
        float sx, cx;
        __sincosf(x, &sx, &cx);
        const float fcut = (d < CUTOFF) ? 0.5f * (cx + 1.0f) : 0.0f;
        float4 q0, q1;
        q0.x = sx;                      // sin(x) UNSCALED (|.|<=1, bf16-safe)
        q0.y = 2.0f * cx;
        q0.z = fcut;
        q0.w = unit_r[3 * e + 0];
        q1.x = unit_r[3 * e + 1];
        q1.y = unit_r[3 * e + 2];
        q1.z = __int_as_float(src);
        q1.w = fcut / d;                // fp32 scale applied in epilogue
        float4* pk = (float4*)(pack + ((size_t)dst * CAP + slot) * 8);
        pk[0] = q0;
        pk[1] = q1;
        return;
    }

    if (b >= EB + MB) {                 // ---- vcast: v_i fp32 -> fp16 record
        const int idx = (b - EB - MB) * 256 + tid;   // (node*128 + f)
        if (idx >= N * F) return;
        const int node = idx >> 7, f = idx & 127;
        const float* vs = v_i + (size_t)node * THREEF + 3 * f;
        _Float16* gp = gh + (size_t)node * 768 + 6 * f + 3;
        gp[0] = (_Float16)vs[0];
        gp[1] = (_Float16)vs[1];
        gp[2] = (_Float16)vs[2];
        return;
    }

    // ---- mlp
    const int wave = tid >> 6;
    const int lane = tid & 63;
    const int m    = lane & 15;
    const int quad = lane >> 4;
    const int node0 = (b - EB) * 16;
    if (node0 >= N) return;

    bf16x8 a1[4];
    #pragma unroll
    for (int kb = 0; kb < 4; ++kb) {
        const float* hp = h + (size_t)(node0 + m) * F + kb * 32 + quad * 8;
        const float4 x0 = *(const float4*)hp;
        const float4 x1 = *(const float4*)(hp + 4);
        bf16x8 a;
        a[0] = (__bf16)x0.x; a[1] = (__bf16)x0.y;
        a[2] = (__bf16)x0.z; a[3] = (__bf16)x0.w;
        a[4] = (__bf16)x1.x; a[5] = (__bf16)x1.y;
        a[6] = (__bf16)x1.z; a[7] = (__bf16)x1.w;
        a1[kb] = a;
    }

    // W1 + silu: 8 ct tiles, 2 per wave, into shared t
    #pragma unroll
    for (int c2 = 0; c2 < 2; ++c2) {
        const int ct = wave * 2 + c2;
        f32x4 acc = {0.0f, 0.0f, 0.0f, 0.0f};
        #pragma unroll
        for (int kb = 0; kb < 4; ++kb) {
            const bf16x8 bb =
                *(const bf16x8*)(W1T + (size_t)(ct * 16 + m) * F + kb * 32 + quad * 8);
            acc = __builtin_amdgcn_mfma_f32_16x16x32_bf16(a1[kb], bb, acc, 0, 0, 0);
        }
        const int col = ct * 16 + m;
        const float bb = b1[col];
        #pragma unroll
        for (int reg = 0; reg < 4; ++reg) {
            const float x = acc[reg] + bb;
            const float s = x / (1.0f + __expf(-x));
            t_lds[(quad * 4 + reg) * TLDS_STRIDE + col] = (__bf16)s;
        }
    }
    __syncthreads();

    bf16x8 a2[4];
    #pragma unroll
    for (int kb = 0; kb < 4; ++kb)
        a2[kb] = *(const bf16x8*)&t_lds[m * TLDS_STRIDE + kb * 32 + quad * 8];

    // W2: 24 ct tiles, 6 per wave; phi written fp16 into the combined record
    #pragma unroll
    for (int c6 = 0; c6 < 6; ++c6) {
        const int ct = c6 * 4 + wave;
        f32x4 acc = {0.0f, 0.0f, 0.0f, 0.0f};
        #pragma unroll
        for (int kb = 0; kb < 4; ++kb) {
            const bf16x8 bb =
                *(const bf16x8*)(W2T + (size_t)(ct * 16 + m) * F + kb * 32 + quad * 8);
            acc = __builtin_amdgcn_mfma_f32_16x16x32_bf16(a2[kb], bb, acc, 0, 0, 0);
        }
        const int col   = ct * 16 + m;
        const int plane = col >> 7;
        const int fc    = col & 127;
        const float bb  = b2[col];
        #pragma unroll
        for (int reg = 0; reg < 4; ++reg) {
            const int row = quad * 4 + reg;
            gh[(size_t)(node0 + row) * 768 + 6 * fc + plane] =
                (_Float16)(acc[reg] + bb);
        }
    }
}

// ---------------------------------------------------------------------------
// Gather: 256 threads = 2 nodes/block. R12: RBF contraction moved onto the
// IDLE matrix pipe (MfmaUtil was 0.0 in all 12 rounds while VALU ~88us was
// the measured floor: R8 VALU/1.45 -> null at old traffic; R10 traffic/2 ->
// -15%; R11 occupancy -> null).
// Per 16-edge chunk: R[16][32] bf16 (UNSCALED sines, relative-accurate) ->
// 12 MFMAs/wave vs W2C[384][32] -> A_lds fp16; per-edge loop = 3 A-reads +
// 3 gather dwords + 8 fma (~22 VALU vs ~75). fcut/d scale + fcut*br bias
// applied in fp32 in the epilogue. Chunk count = max over the block's 2
// nodes (barrier-uniform); pad rows are zeros -> contribute exactly 0.
// ---------------------------------------------------------------------------
__global__ __launch_bounds__(256) void gather_kernel(
    const _Float16* __restrict__ gh,     // (N,128,6) {phi0,phi1,phi2,vx,vy,vz}
    const __bf16* __restrict__ W2C,      // (384,32) [col][k]
    const float* __restrict__ br,        // (384)
    const int*   __restrict__ cnt,       // (N)
    const float* __restrict__ pack,      // (N,CAP,8)
    float* __restrict__ dh,              // (N,128)
    float* __restrict__ dv,              // (N,128,3)
    int N)
{
    __shared__ float4   s_pack[2][CAP * 2];       // 4 KB
    __shared__ __bf16   R_lds[2][16][40];         // 2.5 KB (pad 40)
    __shared__ _Float16 A_lds[2][16][ASTRIDE];    // 24.5 KB (pad 392)

    const int tid   = threadIdx.x;
    const int half  = tid >> 7;
    const int f     = tid & 127;
    const int wave  = tid >> 6;          // 0..3
    const int lane  = tid & 63;
    const int m     = lane & 15;
    const int quad  = lane >> 4;
    const int whalf = wave >> 1;         // which node this wave's MFMA serves
    const int wsub  = wave & 1;          // which 12 N-tiles

    const int nb   = blockIdx.x * 2;
    const int node = nb + half;

    const int dg0 = min(cnt[nb], CAP);
    const int dg1 = min(cnt[nb + 1], CAP);
    const int deg = half ? dg1 : dg0;
    const int dmax = dg0 > dg1 ? dg0 : dg1;
    const int nchunk = (dmax + 15) >> 4;          // uniform across the block
    const int degR = nchunk * 16;

    {   // stage pack rows; zero the pad slots up to degR
        const float4* srcp = (const float4*)(pack + (size_t)node * CAP * 8);
        if (f < 2 * degR) {
            float4 v = make_float4(0.0f, 0.0f, 0.0f, 0.0f);
            if (f < 2 * deg) v = srcp[f];
            s_pack[half][f] = v;
        }
    }
    __syncthreads();

    const float br0 = br[f], br1 = br[f + 128], br2 = br[f + 256];

    float dh_acc = 0.0f, dvx = 0.0f, dvy = 0.0f, dvz = 0.0f;

    for (int c0 = 0; c0 < degR; c0 += 16) {
        // ---- R build: one thread per chunk edge (f<16 of each half).
        // Pad rows: sx=twoc=0 -> all-zero sines.
        if (f < 16) {
            const float* q = (const float*)&s_pack[half][2 * (c0 + f)];
            const float twoc = q[1];
            float rp = 0.0f, rc = q[0];
            __bf16* rr = &R_lds[half][f][0];
            rr[0] = (__bf16)rc;
            #pragma unroll
            for (int n = 1; n < N_RBF; ++n) {
                const float rn = fmaf(twoc, rc, -rp);
                rp = rc; rc = rn;
                rr[n] = (__bf16)rn;
            }
            #pragma unroll
            for (int n = N_RBF; n < 32; ++n) rr[n] = (__bf16)0.0f;
        }
        __syncthreads();

        // ---- MFMA: 2 waves per node, 12 N-tiles each (A-frag shared)
        const bf16x8 af = *(const bf16x8*)&R_lds[whalf][m][quad * 8];
        #pragma unroll
        for (int t = 0; t < 12; ++t) {
            const int tile = wsub * 12 + t;
            const bf16x8 bf =
                *(const bf16x8*)(W2C + (size_t)(tile * 16 + m) * 32 + quad * 8);
            f32x4 acc = {0.0f, 0.0f, 0.0f, 0.0f};
            acc = __builtin_amdgcn_mfma_f32_16x16x32_bf16(af, bf, acc, 0, 0, 0);
            const int colg = tile * 16 + m;
            #pragma unroll
            for (int r = 0; r < 4; ++r)
                A_lds[whalf][quad * 4 + r][colg] = (_Float16)acc[r];
        }
        __syncthreads();

        // ---- accumulate the 16 chunk edges (pads contribute exactly 0)
        #pragma unroll 4
        for (int j = 0; j < 16; ++j) {
            const float* q = (const float*)&s_pack[half][2 * (c0 + j)];
            const float fcut = q[2], ux = q[3], uy = q[4], uz = q[5];
            const float scl  = q[7];
            const int src = __builtin_amdgcn_readfirstlane(__float_as_int(q[6]));

            const float a0 = fmaf(scl, (float)A_lds[half][j][f],       fcut * br0);
            const float a1 = fmaf(scl, (float)A_lds[half][j][128 + f], fcut * br1);
            const float a2 = fmaf(scl, (float)A_lds[half][j][256 + f], fcut * br2);

            const unsigned int* gb =
                (const unsigned int*)(gh + (size_t)src * 768) + 3 * f;
            const unsigned int d0 = gb[0], d1 = gb[1], d2 = gb[2];

            const float f1 = loh(d0) * a0;
            const float f2 = hih(d0) * a1;
            const float f3 = loh(d1) * a2;
            dh_acc += f3;
            dvx = fmaf(f1, ux, fmaf(f2, hih(d1), dvx));
            dvy = fmaf(f1, uy, fmaf(f2, loh(d2), dvy));
            dvz = fmaf(f1, uz, fmaf(f2, hih(d2), dvz));
        }
        __syncthreads();
    }

    dh[(size_t)node * F + f] = dh_acc;
    float* dvp = dv + (size_t)node * THREEF + 3 * f;
    dvp[0] = dvx;
    dvp[1] = dvy;
    dvp[2] = dvz;
}

extern "C" void kernel_launch(void* const* d_in, const int* in_sizes, int n_in,
                              void* d_out, int out_size, void* d_ws, size_t ws_size,
                              hipStream_t stream) {
    const float* h_i    = (const float*)d_in[0];
    const float* v_i    = (const float*)d_in[1];
    const float* d_ij   = (const float*)d_in[2];
    const float* unit_r = (const float*)d_in[3];
    const int*   nbrs   = (const int*)  d_in[4];
    const float* W1     = (const float*)d_in[5];
    const float* b1     = (const float*)d_in[6];
    const float* W2     = (const float*)d_in[7];
    const float* b2     = (const float*)d_in[8];
    const float* Wr     = (const float*)d_in[9];
    const float* br     = (const float*)d_in[10];

    const int N = in_sizes[0] / F;       // 20000
    const int E = in_sizes[2];           // 320000

    float* dh = (float*)d_out;              // (N,128)
    float* dv = dh + (size_t)N * F;         // (N,128,3)

    // workspace: gh (N*768 fp16) | pack (N*CAP*8 f32) | cnt | W1T | W2T | W2C
    _Float16* gh = (_Float16*)d_ws;                                  // 30.7 MB
    float* pack  = (float*)((char*)d_ws + (size_t)N * 768 * sizeof(_Float16));
    int*    cnt  = (int*)(pack + (size_t)N * CAP * 8);     // 80 KB
    __bf16* W1T  = (__bf16*)(cnt + N);                     // 32 KB
    __bf16* W2T  = W1T + 128 * 128;                        // 96 KB
    __bf16* W2C  = W2T + 384 * 128;                        // 24 KB

    const int EB = (E + 255) / 256;      // 1250 build blocks
    const int MB = (N + 15) / 16;        // 1250 mlp blocks
    const int VB = (N * F + 255) / 256;  // 10000 vcast blocks
    const int ZB = ((N + 3) / 4 + 255) / 256;   // cnt-zero blocks (20)

    init_kernel<<<304 + ZB, 256, 0, stream>>>(W1, W2, Wr, W1T, W2T, W2C,
                                              cnt, N);
    work_kernel<<<EB + MB + VB, 256, 0, stream>>>(d_ij, unit_r, nbrs, v_i,
                                                  cnt, pack, h_i, W1T, b1,
                                                  W2T, b2, gh, E, EB, MB, N);
    gather_kernel<<<N / 2, 256, 0, stream>>>(gh, W2C, br, cnt, pack,
                                             dh, dv, N);
}

// Round 13
// 270.903 us; speedup vs baseline: 1.1860x; 1.1860x over previous
//
#include <hip/hip_runtime.h>
#include <math.h>

#define F 128
#define THREEF 384
#define N_RBF 20
#define CUTOFF 5.0f
#define CAP 64
#define TLDS_STRIDE 136   // shorts; 272 B row: 16B-aligned, ~2-way banks (free)

typedef __bf16 bf16x8 __attribute__((ext_vector_type(8)));
typedef float  f32x4  __attribute__((ext_vector_type(4)));
typedef float  f32x2  __attribute__((ext_vector_type(2)));
typedef _Float16 f16x2 __attribute__((ext_vector_type(2)));

static __device__ __forceinline__ float loh(unsigned int u) {
    const f16x2 h = __builtin_bit_cast(f16x2, u);
    return (float)h[0];
}
static __device__ __forceinline__ float hih(unsigned int u) {
    const f16x2 h = __builtin_bit_cast(f16x2, u);
    return (float)h[1];
}

// ---------------------------------------------------------------------------
// Init:
//   blocks [0,256)    : wcast — W1,W2 -> bf16 k-major
//   blocks [256,264)  : wrt — chunked transpose of Wr for gather
//   blocks [264,...)  : zero cnt (int4 stores)
// ---------------------------------------------------------------------------
__global__ __launch_bounds__(256) void init_kernel(
    const float* __restrict__ W1, const float* __restrict__ W2,
    const float* __restrict__ Wr,
    __bf16* __restrict__ W1T, __bf16* __restrict__ W2T,
    float* __restrict__ WrT, int* __restrict__ cnt, int N)
{
    const int tid = threadIdx.x;
    const int b   = blockIdx.x;

    if (b < 256) {                      // ---- wcast
        const int idx = b * 256 + tid;
        if (idx < 128 * 128) {
            const int n = idx >> 7, k = idx & 127;
            W1T[idx] = (__bf16)W1[k * F + n];
        }
        if (idx < 384 * 128) {
            const int n = idx >> 7, k = idx & 127;
            W2T[idx] = (__bf16)W2[k * THREEF + n];
        }
    } else if (b < 264) {               // ---- wrt
        const int idx = (b - 256) * 256 + tid;   // 0..2047
        if (idx >= 5 * 3 * 128) return;
        const int f  = idx & 127;
        const int c  = (idx >> 7) % 3;
        const int n4 = idx / (3 * 128);
        float4 v;
        v.x = Wr[(4 * n4 + 0) * THREEF + c * 128 + f];
        v.y = Wr[(4 * n4 + 1) * THREEF + c * 128 + f];
        v.z = Wr[(4 * n4 + 2) * THREEF + c * 128 + f];
        v.w = Wr[(4 * n4 + 3) * THREEF + c * 128 + f];
        ((float4*)WrT)[idx] = v;
    } else {                            // ---- zero cnt
        const int i = (b - 264) * 256 + tid;
        if (i < (N + 3) / 4) {
            int4 z; z.x = 0; z.y = 0; z.z = 0; z.w = 0;
            ((int4*)cnt)[i] = z;
        }
    }
}

// ---------------------------------------------------------------------------
// Work (build ∥ mlp ∥ vcast as CONCURRENT block ranges):
//   blocks [0, EB)           : build — pack row at (dst,slot):
//                              {s1, 2cos(x), fcut, ux, uy, uz, src, 0}
//   blocks [EB, EB+MB)       : mlp — phi via bf16 MFMA, fp16 into gh record
//   blocks [EB+MB, EB+MB+VB) : vcast — v_i fp32 -> fp16 into gh record
// gh = (N,128,6) fp16 {phi0,phi1,phi2,vx,vy,vz} (R10-verified: FETCH /2).
// R13: gh stores coalesced. mlp thread (wave w, lane m) computes all 3
// planes of the SAME fc across ct ∈ {p*8 + g*4 + w} -> buffer 3 accs, emit
// one dword {phi0,phi1} + one half {phi2} per (row,fc) instead of 3 scattered
// half-stores. vcast: one half {vx} + one dword {vy,vz} instead of 3 halves.
// ---------------------------------------------------------------------------
__global__ __launch_bounds__(256) void work_kernel(
    const float* __restrict__ d_ij, const float* __restrict__ unit_r,
    const int* __restrict__ nbrs, const float* __restrict__ v_i,
    int* __restrict__ cnt, float* __restrict__ pack,
    const float* __restrict__ h,
    const __bf16* __restrict__ W1T, const float* __restrict__ b1,
    const __bf16* __restrict__ W2T, const float* __restrict__ b2,
    _Float16* __restrict__ gh, int E, int EB, int MB, int N)
{
    __shared__ __bf16 t_lds[16 * TLDS_STRIDE];   // mlp only; 4.3 KB

    const int tid = threadIdx.x;
    const int b   = blockIdx.x;

    if (b < EB) {                       // ---- build
        const int e = b * 256 + tid;
        if (e >= E) return;
        const int2 nb = ((const int2*)nbrs)[e];
        const int dst = nb.x;
        const int src = nb.y;
        const int slot = atomicAdd(&cnt[dst], 1);
        if (slot >= CAP) return;

        const float d = d_ij[e];
        const float x = (float)M_PI * d * (1.0f / CUTOFF);
        float sx, cx;
        __sincosf(x, &sx, &cx);
        const float fcut = (d < CUTOFF) ? 0.5f * (cx + 1.0f) : 0.0f;
        float4 q0, q1;
        q0.x = sx * fcut / d;           // rbff_1; recurrence keeps fcut/d scale
        q0.y = 2.0f * cx;
        q0.z = fcut;
        q0.w = unit_r[3 * e + 0];
        q1.x = unit_r[3 * e + 1];
        q1.y = unit_r[3 * e + 2];
        q1.z = __int_as_float(src);
        q1.w = 0.0f;
        float4* pk = (float4*)(pack + ((size_t)dst * CAP + slot) * 8);
        pk[0] = q0;
        pk[1] = q1;
        return;
    }

    if (b >= EB + MB) {                 // ---- vcast: v_i fp32 -> fp16 record
        const int idx = (b - EB - MB) * 256 + tid;   // (node*128 + f)
        if (idx >= N * F) return;
        const int node = idx >> 7, f = idx & 127;
        const float* vs = v_i + (size_t)node * THREEF + 3 * f;
        _Float16* gp = gh + (size_t)node * 768 + 6 * f;
        gp[3] = (_Float16)vs[0];                       // vx (half)
        f16x2 h45;
        h45[0] = (_Float16)vs[1];
        h45[1] = (_Float16)vs[2];
        *(f16x2*)(gp + 4) = h45;                       // vy,vz (dword, 4B-al)
        return;
    }

    // ---- mlp
    const int wave = tid >> 6;
    const int lane = tid & 63;
    const int m    = lane & 15;
    const int quad = lane >> 4;
    const int node0 = (b - EB) * 16;
    if (node0 >= N) return;

    bf16x8 a1[4];
    #pragma unroll
    for (int kb = 0; kb < 4; ++kb) {
        const float* hp = h + (size_t)(node0 + m) * F + kb * 32 + quad * 8;
        const float4 x0 = *(const float4*)hp;
        const float4 x1 = *(const float4*)(hp + 4);
        bf16x8 a;
        a[0] = (__bf16)x0.x; a[1] = (__bf16)x0.y;
        a[2] = (__bf16)x0.z; a[3] = (__bf16)x0.w;
        a[4] = (__bf16)x1.x; a[5] = (__bf16)x1.y;
        a[6] = (__bf16)x1.z; a[7] = (__bf16)x1.w;
        a1[kb] = a;
    }

    // W1 + silu: 8 ct tiles, 2 per wave, into shared t
    #pragma unroll
    for (int c2 = 0; c2 < 2; ++c2) {
        const int ct = wave * 2 + c2;
        f32x4 acc = {0.0f, 0.0f, 0.0f, 0.0f};
        #pragma unroll
        for (int kb = 0; kb < 4; ++kb) {
            const bf16x8 bb =
                *(const bf16x8*)(W1T + (size_t)(ct * 16 + m) * F + kb * 32 + quad * 8);
            acc = __builtin_amdgcn_mfma_f32_16x16x32_bf16(a1[kb], bb, acc, 0, 0, 0);
        }
        const int col = ct * 16 + m;
        const float bb = b1[col];
        #pragma unroll
        for (int reg = 0; reg < 4; ++reg) {
            const float x = acc[reg] + bb;
            const float s = x / (1.0f + __expf(-x));
            t_lds[(quad * 4 + reg) * TLDS_STRIDE + col] = (__bf16)s;
        }
    }
    __syncthreads();

    bf16x8 a2[4];
    #pragma unroll
    for (int kb = 0; kb < 4; ++kb)
        a2[kb] = *(const bf16x8*)&t_lds[m * TLDS_STRIDE + kb * 32 + quad * 8];

    // W2: 24 ct tiles = 2 fc-groups x 3 planes per wave; coalesced gh stores
    #pragma unroll
    for (int g = 0; g < 2; ++g) {
        f32x4 accp[3];
        #pragma unroll
        for (int p = 0; p < 3; ++p) {
            const int ct = p * 8 + g * 4 + wave;   // col = p*128 + g*64+w*16+m
            f32x4 acc = {0.0f, 0.0f, 0.0f, 0.0f};
            #pragma unroll
            for (int kb = 0; kb < 4; ++kb) {
                const bf16x8 bb =
                    *(const bf16x8*)(W2T + (size_t)(ct * 16 + m) * F + kb * 32 + quad * 8);
                acc = __builtin_amdgcn_mfma_f32_16x16x32_bf16(a2[kb], bb, acc, 0, 0, 0);
            }
            const float bb = b2[ct * 16 + m];
            #pragma unroll
            for (int reg = 0; reg < 4; ++reg) acc[reg] += bb;
            accp[p] = acc;
        }
        const int fc = g * 64 + wave * 16 + m;
        #pragma unroll
        for (int reg = 0; reg < 4; ++reg) {
            const int row = quad * 4 + reg;
            _Float16* gp = gh + (size_t)(node0 + row) * 768 + 6 * fc;
            f16x2 h01;
            h01[0] = (_Float16)accp[0][reg];
            h01[1] = (_Float16)accp[1][reg];
            *(f16x2*)gp = h01;                       // phi0,phi1 (dword, 4B-al)
            gp[2] = (_Float16)accp[2][reg];          // phi2 (half)
        }
    }
}

// ---------------------------------------------------------------------------
// Gather: 256 threads = 2 nodes/block. EXACT R10 revert (best verified:
// 121 us, VGPR 64 no-spill, FETCH 218 MB): 4-edge blocking, packed f32x2
// Chebyshev double-step, fp16 combined record (3 dwords/lane-edge), SALU
// gather addresses, amdgpu_waves_per_eu(2,4).
// R12's MFMA offload regressed (barriers >> work at deg~16); R11 showed the
// occupancy knob is null. This body is the measured floor structure.
// ---------------------------------------------------------------------------
__global__ __launch_bounds__(256)
__attribute__((amdgpu_waves_per_eu(2, 4)))
void gather_kernel(
    const _Float16* __restrict__ gh,     // (N,128,6) {phi0,phi1,phi2,vx,vy,vz}
    const float* __restrict__ WrT,       // (5,3,128,4) chunked transpose
    const float* __restrict__ br,        // (384)
    const int*   __restrict__ cnt,       // (N)
    const float* __restrict__ pack,      // (N,CAP,8)
    float* __restrict__ dh,              // (N,128)
    float* __restrict__ dv,              // (N,128,3)
    int N)
{
    __shared__ float4 s_pack[2][CAP * 2];   // 4 KB

    const int tid  = threadIdx.x;
    const int half = tid >> 7;
    const int f    = tid & 127;
    const int node = blockIdx.x * 2 + half;

    const int deg0 = cnt[node];
    const int deg  = deg0 < CAP ? deg0 : CAP;
    const int degR = (deg + 3) & ~3;         // pad to 4-edge blocks (<= CAP)

    {   // stage this node's pack rows; zero the pad slots
        const float4* srcp = (const float4*)(pack + (size_t)node * CAP * 8);
        if (f < 2 * degR) {
            float4 v = make_float4(0.0f, 0.0f, 0.0f, 0.0f);
            if (f < 2 * deg) v = srcp[f];
            s_pack[half][f] = v;
        }
    }
    __syncthreads();

    const float br0 = br[f], br1 = br[f + 128], br2 = br[f + 256];
    const f32x4* wT = (const f32x4*)WrT;   // wT[(n4*3 + c)*128 + f]

    float dh_acc = 0.0f, dvx = 0.0f, dvy = 0.0f, dvz = 0.0f;

    for (int i0 = 0; i0 < degR; i0 += 4) {
        // ---- prologue: per-edge seeds + issue all gather loads (SALU addr)
        float s1[4], twoc[4], fcut[4], ux[4], uy[4], uz[4];
        float ph0[4], ph1[4], ph2[4], vx[4], vy[4], vz[4];
        #pragma unroll
        for (int j = 0; j < 4; ++j) {
            const float4 q0 = s_pack[half][2 * (i0 + j)];
            const float4 q1 = s_pack[half][2 * (i0 + j) + 1];
            s1[j] = q0.x; twoc[j] = q0.y; fcut[j] = q0.z;
            ux[j] = q0.w; uy[j] = q1.x;   uz[j] = q1.y;
            const int src = __builtin_amdgcn_readfirstlane(__float_as_int(q1.z));
            const unsigned int* gb =
                (const unsigned int*)(gh + (size_t)src * 768) + 3 * f;
            const unsigned int d0 = gb[0], d1 = gb[1], d2 = gb[2];
            ph0[j] = loh(d0); ph1[j] = hih(d0);
            ph2[j] = loh(d1); vx[j]  = hih(d1);
            vy[j]  = loh(d2); vz[j]  = hih(d2);
        }

        // ---- contraction state: packed Chebyshev double-step (R8-verified)
        f32x2 t2[4], rc[4], rp[4], A0[4], A1[4], A2[4];
        #pragma unroll
        for (int j = 0; j < 4; ++j) {
            const float t2s = fmaf(twoc[j], twoc[j], -2.0f);
            t2[j][0] = t2s;      t2[j][1] = t2s;
            rc[j][0] = s1[j];    rc[j][1] = twoc[j] * s1[j];   // (r1, r2)
            rp[j][0] = -s1[j];   rp[j][1] = 0.0f;              // (r-1, r0)
            A0[j] = (f32x2){0.0f, 0.0f};
            A1[j] = (f32x2){0.0f, 0.0f};
            A2[j] = (f32x2){0.0f, 0.0f};
        }

        #pragma unroll
        for (int n4 = 0; n4 < 5; ++n4) {
            const f32x4 w0 = wT[(n4 * 3 + 0) * 128 + f];
            const f32x4 w1 = wT[(n4 * 3 + 1) * 128 + f];
            const f32x4 w2 = wT[(n4 * 3 + 2) * 128 + f];
            const f32x2 w0lo = __builtin_shufflevector(w0, w0, 0, 1);
            const f32x2 w1lo = __builtin_shufflevector(w1, w1, 0, 1);
            const f32x2 w2lo = __builtin_shufflevector(w2, w2, 0, 1);
            const f32x2 w0hi = __builtin_shufflevector(w0, w0, 2, 3);
            const f32x2 w1hi = __builtin_shufflevector(w1, w1, 2, 3);
            const f32x2 w2hi = __builtin_shufflevector(w2, w2, 2, 3);
            #pragma unroll
            for (int j = 0; j < 4; ++j) {
                A0[j] = __builtin_elementwise_fma(rc[j], w0lo, A0[j]);
                A1[j] = __builtin_elementwise_fma(rc[j], w1lo, A1[j]);
                A2[j] = __builtin_elementwise_fma(rc[j], w2lo, A2[j]);
                f32x2 rn = __builtin_elementwise_fma(t2[j], rc[j], -rp[j]);
                rp[j] = rc[j]; rc[j] = rn;
                A0[j] = __builtin_elementwise_fma(rc[j], w0hi, A0[j]);
                A1[j] = __builtin_elementwise_fma(rc[j], w1hi, A1[j]);
                A2[j] = __builtin_elementwise_fma(rc[j], w2hi, A2[j]);
                rn = __builtin_elementwise_fma(t2[j], rc[j], -rp[j]);
                rp[j] = rc[j]; rc[j] = rn;
            }
        }

        // ---- epilogue
        #pragma unroll
        for (int j = 0; j < 4; ++j) {
            const float a0 = fmaf(br0, fcut[j], A0[j][0] + A0[j][1]);
            const float a1 = fmaf(br1, fcut[j], A1[j][0] + A1[j][1]);
            const float a2 = fmaf(br2, fcut[j], A2[j][0] + A2[j][1]);
            const float f1 = ph0[j] * a0;
            const float f2 = ph1[j] * a1;
            const float f3 = ph2[j] * a2;
            dh_acc += f3;
            dvx = fmaf(f1, ux[j], fmaf(f2, vx[j], dvx));
            dvy = fmaf(f1, uy[j], fmaf(f2, vy[j], dvy));
            dvz = fmaf(f1, uz[j], fmaf(f2, vz[j], dvz));
        }
    }

    dh[(size_t)node * F + f] = dh_acc;
    float* dvp = dv + (size_t)node * THREEF + 3 * f;
    dvp[0] = dvx;
    dvp[1] = dvy;
    dvp[2] = dvz;
}

extern "C" void kernel_launch(void* const* d_in, const int* in_sizes, int n_in,
                              void* d_out, int out_size, void* d_ws, size_t ws_size,
                              hipStream_t stream) {
    const float* h_i    = (const float*)d_in[0];
    const float* v_i    = (const float*)d_in[1];
    const float* d_ij   = (const float*)d_in[2];
    const float* unit_r = (const float*)d_in[3];
    const int*   nbrs   = (const int*)  d_in[4];
    const float* W1     = (const float*)d_in[5];
    const float* b1     = (const float*)d_in[6];
    const float* W2     = (const float*)d_in[7];
    const float* b2     = (const float*)d_in[8];
    const float* Wr     = (const float*)d_in[9];
    const float* br     = (const float*)d_in[10];

    const int N = in_sizes[0] / F;       // 20000
    const int E = in_sizes[2];           // 320000

    float* dh = (float*)d_out;              // (N,128)
    float* dv = dh + (size_t)N * F;         // (N,128,3)

    // workspace: gh (N*768 fp16) | pack (N*CAP*8 f32) | WrT | cnt | W1T | W2T
    _Float16* gh = (_Float16*)d_ws;                                  // 30.7 MB
    float* pack  = (float*)((char*)d_ws + (size_t)N * 768 * sizeof(_Float16));
    float*  WrT  = pack + (size_t)N * CAP * 8;             // 30 KB
    int*    cnt  = (int*)(WrT + 5 * 3 * 128 * 4);          // 80 KB
    __bf16* W1T  = (__bf16*)(cnt + N);                     // 32 KB
    __bf16* W2T  = W1T + 128 * 128;                        // 96 KB

    const int EB = (E + 255) / 256;      // 1250 build blocks
    const int MB = (N + 15) / 16;        // 1250 mlp blocks
    const int VB = (N * F + 255) / 256;  // 10000 vcast blocks
    const int ZB = ((N + 3) / 4 + 255) / 256;   // cnt-zero blocks (20)

    init_kernel<<<264 + ZB, 256, 0, stream>>>(W1, W2, Wr, W1T, W2T, WrT,
                                              cnt, N);
    work_kernel<<<EB + MB + VB, 256, 0, stream>>>(d_ij, unit_r, nbrs, v_i,
                                                  cnt, pack, h_i, W1T, b1,
                                                  W2T, b2, gh, E, EB, MB, N);
    gather_kernel<<<N / 2, 256, 0, stream>>>(gh, WrT, br, cnt, pack,
                                             dh, dv, N);
}